// Round 2
// baseline (333.512 us; speedup 1.0000x reference)
//
#include <hip/hip_runtime.h>

// Problem constants (fixed by reference setup_inputs)
#define B_  8
#define T_  1000
#define F_  257
#define P_  (T_ * F_)               // 257000 floats per (T,F) plane
#define SQ3_2 0.8660254037844386f

// Flat-tiling parameters
#define THREADS 512
#define VEC     4
#define CHUNK   (THREADS * VEC)     // 2048 floats of a plane per block
#define NBLK    ((P_ + CHUNK - 1) / CHUNK)   // 126
#define XROWS   11                  // max t-span (9) + 2 halo rows
#define XCOLS   (F_ + 2)            // f = -1 .. 257
#define OROWS   9                   // max t-span of outputs per block

// ---------------------------------------------------------------------------
// Flat-index fused kernel: each block owns a contiguous, 16B-aligned chunk of
// 2048 floats of the (T,F) plane (per b). The dominant 222 MB m stream is
// read as 27 aligned global_load_dwordx4 per thread (1 KB/wave, zero
// over-fetch, no inter-block cache-line sharing). x halo (<=11 t-rows x full
// F) staged into LDS coalesced along t; output transposed through the SAME
// LDS buffer (reused after a barrier) so global writes coalesce along t.
// ---------------------------------------------------------------------------
__global__ __launch_bounds__(THREADS)
void ccm_fused(const float* __restrict__ m, const float2* __restrict__ x,
               float2* __restrict__ out) {
    // 2849 float2 = 22.8 KB; also reused for out staging (needs 9*257=2313)
    __shared__ float2 buf[XROWS * XCOLS];

    const int b      = blockIdx.z;
    const int s      = blockIdx.x * CHUNK;          // first flat index owned
    const int send   = min(s + CHUNK, P_);
    const int t_lo   = s / F_;                      // uniform per block
    const int t_base = t_lo - 2;                    // first staged t row
    const int tid    = threadIdx.x;

    // ---- Stage x halo: buf[r*XCOLS + j] = xp[t_base + r, f = j-1] ----
    // idx = j*XROWS + r: r fast => consecutive lanes hit consecutive t
    // (x is contiguous in t), 88 B contiguous per f-row.
    const float2* xb = x + (size_t)b * (F_ * T_);
    for (int idx = tid; idx < XROWS * XCOLS; idx += THREADS) {
        const int j  = idx / XROWS;
        const int r  = idx - j * XROWS;
        const int tt = t_base + r;
        const int ff = j - 1;
        float2 v = make_float2(0.f, 0.f);
        if (tt >= 0 && tt < T_ && ff >= 0 && ff < F_)
            v = xb[(size_t)ff * T_ + tt];
        buf[r * XCOLS + j] = v;
    }
    __syncthreads();

    // ---- Compute 4 consecutive-flat outputs per thread ----
    const int  p0     = s + tid * VEC;   // multiple of 4; P_ is too
    const bool active = p0 < P_;

    float accr[VEC], acci[VEC];
    int   te[VEC], fe[VEC], base[VEC];
    #pragma unroll
    for (int e = 0; e < VEC; ++e) { accr[e] = 0.f; acci[e] = 0.f; te[e] = 0; fe[e] = 0; }

    if (active) {
        te[0] = p0 / F_;
        fe[0] = p0 - te[0] * F_;
        #pragma unroll
        for (int e = 1; e < VEC; ++e) {      // handle row wrap branchlessly
            te[e] = te[e - 1];
            fe[e] = fe[e - 1] + 1;
            if (fe[e] == F_) { fe[e] = 0; ++te[e]; }
        }
        // tap(c) = buf[(te - t_lo + c/3)*XCOLS + fe + c%3]
        #pragma unroll
        for (int e = 0; e < VEC; ++e)
            base[e] = (te[e] - t_lo) * XCOLS + fe[e];

        const float* mb = m + (size_t)b * 27 * P_ + p0;
        #pragma unroll
        for (int c = 0; c < 9; ++c) {
            const float4 m0 = *(const float4*)(mb + (size_t)(c)      * P_);
            const float4 m1 = *(const float4*)(mb + (size_t)(c + 9)  * P_);
            const float4 m2 = *(const float4*)(mb + (size_t)(c + 18) * P_);
            const int off = (c / 3) * XCOLS + (c % 3);
            const float* f0v = (const float*)&m0;
            const float* f1v = (const float*)&m1;
            const float* f2v = (const float*)&m2;
            #pragma unroll
            for (int e = 0; e < VEC; ++e) {
                const float  hr = f0v[e] - 0.5f * (f1v[e] + f2v[e]);
                const float  hi = SQ3_2 * (f1v[e] - f2v[e]);
                const float2 xv = buf[base[e] + off];
                accr[e] = fmaf(hr,  xv.x, accr[e]);
                accr[e] = fmaf(-hi, xv.y, accr[e]);
                acci[e] = fmaf(hr,  xv.y, acci[e]);
                acci[e] = fmaf(hi,  xv.x, acci[e]);
            }
        }
    }

    __syncthreads();   // all taps consumed; reuse buf for output staging

    if (active) {
        #pragma unroll
        for (int e = 0; e < VEC; ++e)
            buf[(te[e] - t_lo) * F_ + fe[e]] = make_float2(accr[e], acci[e]);
    }
    __syncthreads();

    // ---- Transposed write-out: r fast => contiguous t per f-row ----
    float2* ob = out + (size_t)b * (F_ * T_);
    for (int idx = tid; idx < OROWS * F_; idx += THREADS) {
        const int f = idx / OROWS;
        const int r = idx - f * OROWS;
        const int t = t_lo + r;
        const int p = t * F_ + f;
        if (p >= s && p < send)
            ob[(size_t)f * T_ + t] = buf[r * F_ + f];
    }
}

extern "C" void kernel_launch(void* const* d_in, const int* in_sizes, int n_in,
                              void* d_out, int out_size, void* d_ws, size_t ws_size,
                              hipStream_t stream) {
    const float*  m = (const float*)d_in[0];   // (B, 27, T, F) fp32
    const float2* x = (const float2*)d_in[1];  // (B, F, T, 2) fp32 -> float2
    float2* out = (float2*)d_out;              // (B, F, T, 2) fp32 -> float2

    dim3 mb(THREADS);
    dim3 mg(NBLK, 1, B_);                      // 126 x 1 x 8
    ccm_fused<<<mg, mb, 0, stream>>>(m, x, out);
}

// Round 3
// 324.787 us; speedup vs baseline: 1.0269x; 1.0269x over previous
//
#include <hip/hip_runtime.h>

// Problem constants (fixed by reference setup_inputs)
#define B_  8
#define T_  1000
#define F_  257
#define TP_ (T_ * F_)               // plane stride in floats
#define SQ3_2 0.8660254037844386f

#define THREADS 512
#define FW 67                       // xls cols: f = f0-1 .. f0+65

// ---------------------------------------------------------------------------
// R0 structure (conflict-free lane-stride-1 LDS taps), tail-fixed:
//   grid.x = 4 (not 5): block bx==3 covers 65 f-cols (192..256); the f=256
//   column is computed by 8 threads of wave 0 only. Removes the 1000 blocks
//   that had 1/64 active lanes but paid full x-halo staging.
//   x halo staged as aligned float4 (t-runs are 16B-aligned): 335 loads/block
//   instead of 660.
//   out staged through LDS so global writes coalesce along t (64 B chunks).
// ---------------------------------------------------------------------------
__global__ __launch_bounds__(THREADS)
void ccm_fused(const float* __restrict__ m, const float2* __restrict__ x,
               float2* __restrict__ out) {
    __shared__ float2 xls[10 * FW];   // [r][j]: tt = t0+r-2, ff = f0+j-1
    __shared__ float2 stage[8][66];   // output transpose staging (65 used)

    const int  b    = blockIdx.z;
    const int  f0   = blockIdx.x * 64;
    const int  t0   = blockIdx.y * 8;
    const bool LAST = (blockIdx.x == 3);
    const int  tid  = threadIdx.x;
    const int  lf   = tid & 63;       // lane's f within tile (stride-1!)
    const int  lt   = tid >> 6;       // lane's t within tile
    const int  f    = f0 + lf;        // always < 256 (grid.x=4)
    const int  t    = t0 + lt;

    // ---- Stage x halo as float4 (2 consecutive t per load) ----
    // idx enumerates 67 f-rows x 5 float4; q fast => 80 B contiguous per row.
    // tt = t0-2+2q is even and x rows are 8000 B => 16 B aligned.
    const float2* xb = x + (size_t)b * (F_ * T_);
    for (int idx = tid; idx < FW * 5; idx += THREADS) {
        const int j  = idx / 5;
        const int q  = idx - j * 5;
        const int ff = f0 + j - 1;
        const int tt = t0 - 2 + 2 * q;
        float2 v0 = make_float2(0.f, 0.f), v1 = v0;
        if (ff >= 0 && ff < F_ && tt >= 0) {        // tt<0 only (by==0,q==0): both pad
            const float4 v = *(const float4*)(xb + (size_t)ff * T_ + tt);
            v0 = make_float2(v.x, v.y);
            v1 = make_float2(v.z, v.w);
        }
        xls[(2 * q)     * FW + j] = v0;
        xls[(2 * q + 1) * FW + j] = v1;
    }
    __syncthreads();

    // ---- Main compute: 27 m loads, conflict-free LDS taps ----
    float accr = 0.f, acci = 0.f;
    {
        const float* mb = m + ((size_t)b * 27 * T_ + t) * F_ + f;
        #pragma unroll
        for (int c = 0; c < 9; ++c) {
            const float m0 = mb[(size_t)(c)      * TP_];
            const float m1 = mb[(size_t)(c + 9)  * TP_];
            const float m2 = mb[(size_t)(c + 18) * TP_];
            const float hr = m0 - 0.5f * (m1 + m2);
            const float hi = SQ3_2 * (m1 - m2);
            const float2 xv = xls[(lt + c / 3) * FW + (lf + c % 3)];
            accr = fmaf(hr,  xv.x, accr);
            accr = fmaf(-hi, xv.y, accr);
            acci = fmaf(hr,  xv.y, acci);
            acci = fmaf(hi,  xv.x, acci);
        }
    }
    stage[lt][lf] = make_float2(accr, acci);

    // ---- Extra column f=256 (bx==3 only): 8 threads of wave 0 ----
    if (LAST && tid < 8) {
        float ar = 0.f, ai = 0.f;
        const float* mb2 = m + ((size_t)b * 27 * T_ + (t0 + tid)) * F_ + 256;
        #pragma unroll
        for (int c = 0; c < 9; ++c) {
            const float m0 = mb2[(size_t)(c)      * TP_];
            const float m1 = mb2[(size_t)(c + 9)  * TP_];
            const float m2 = mb2[(size_t)(c + 18) * TP_];
            const float hr = m0 - 0.5f * (m1 + m2);
            const float hi = SQ3_2 * (m1 - m2);
            const float2 xv = xls[(tid + c / 3) * FW + (64 + c % 3)];
            ar = fmaf(hr,  xv.x, ar);
            ar = fmaf(-hi, xv.y, ar);
            ai = fmaf(hr,  xv.y, ai);
            ai = fmaf(hi,  xv.x, ai);
        }
        stage[tid][64] = make_float2(ar, ai);
    }
    __syncthreads();

    // ---- Transposed write-out: wt fast => 64 B contiguous t per f-row ----
    const int NC = LAST ? 65 : 64;
    float2* ob = out + (size_t)b * (F_ * T_);
    for (int idx = tid; idx < NC * 8; idx += THREADS) {
        const int wf = idx >> 3;
        const int wt = idx & 7;
        ob[(size_t)(f0 + wf) * T_ + (t0 + wt)] = stage[wt][wf];
    }
}

extern "C" void kernel_launch(void* const* d_in, const int* in_sizes, int n_in,
                              void* d_out, int out_size, void* d_ws, size_t ws_size,
                              hipStream_t stream) {
    const float*  m = (const float*)d_in[0];   // (B, 27, T, F) fp32
    const float2* x = (const float2*)d_in[1];  // (B, F, T, 2) fp32 -> float2
    float2* out = (float2*)d_out;              // (B, F, T, 2) fp32 -> float2

    dim3 mb(THREADS);
    dim3 mg(4, T_ / 8, B_);                    // 4 x 125 x 8
    ccm_fused<<<mg, mb, 0, stream>>>(m, x, out);
}